// Round 1
// baseline (132.190 us; speedup 1.0000x reference)
//
#include <hip/hip_runtime.h>
#include <cmath>

#define DEV static __device__ __forceinline__

namespace {

constexpr int B = 2, S = 512, D = 512, H = 8;   // dh = 64
constexpr int BS = B * S;                        // 1024 token rows
constexpr float EPSF = 1e-5f;
constexpr float MAXN = 1.0f - 1e-3f;             // MAX_NORM / sqrt(c)

DEV float waveSum(float v) {
#pragma unroll
  for (int o = 32; o > 0; o >>= 1) v += __shfl_xor(v, o, 64);
  return v;
}
DEV float waveMax(float v) {
#pragma unroll
  for (int o = 32; o > 0; o >>= 1) v = fmaxf(v, __shfl_xor(v, o, 64));
  return v;
}

// ---------------- logmap0 over full rows (512) -----------------------------
// factor = artanh(min(n, 1-EPS)) / n,  n = max(||x||, EPS)
__global__ __launch_bounds__(256) void logmap_rows(
    const float* __restrict__ q, const float* __restrict__ k,
    const float* __restrict__ v, float* __restrict__ outbase) {
  const float* in = blockIdx.y == 0 ? q : (blockIdx.y == 1 ? k : v);
  float* out = outbase + (size_t)blockIdx.y * BS * D;
  const float* x = in + (size_t)blockIdx.x * D;
  float s = 0.f;
  for (int i = threadIdx.x; i < D; i += 256) { float t = x[i]; s += t * t; }
  __shared__ float sh[4];
  float wsum = waveSum(s);
  if ((threadIdx.x & 63) == 0) sh[threadIdx.x >> 6] = wsum;
  __syncthreads();
  float tot = sh[0] + sh[1] + sh[2] + sh[3];
  float n = fmaxf(sqrtf(tot), EPSF);
  float z = fminf(n, 1.0f - EPSF);
  float fac = 0.5f * logf((1.0f + z) / (1.0f - z)) / n;  // artanh(z)/n
  float* o = out + (size_t)blockIdx.x * D;
  for (int i = threadIdx.x; i < D; i += 256) o[i] = x[i] * fac;
}

// ---------------- C = A @ W^T + b (A: BS x 512, W: 512 x 512) --------------
// blockIdx.z selects (A-slab, W, b, C-slab). 64x64 tile, BK=16, 4x4/thread.
__global__ __launch_bounds__(256) void gemm_at_bias3(
    const float* __restrict__ Abase,
    const float* __restrict__ W0, const float* __restrict__ W1,
    const float* __restrict__ W2,
    const float* __restrict__ b0, const float* __restrict__ b1,
    const float* __restrict__ b2,
    float* __restrict__ Cbase) {
  const int z = blockIdx.z;
  const float* A = Abase + (size_t)z * BS * D;
  const float* W = z == 0 ? W0 : (z == 1 ? W1 : W2);
  const float* bias = z == 0 ? b0 : (z == 1 ? b1 : b2);
  float* C = Cbase + (size_t)z * BS * D;

  __shared__ float As[16][64];  // k-major
  __shared__ float Ws[16][64];
  const int tid = threadIdx.x;
  const int tx = tid & 15, ty = tid >> 4;
  const int i0 = blockIdx.y * 64, j0 = blockIdx.x * 64;
  const int lr = tid >> 2, lc = (tid & 3) * 4;  // tile load mapping

  float acc[4][4] = {};
  for (int kt = 0; kt < D; kt += 16) {
    float4 av = *reinterpret_cast<const float4*>(A + (size_t)(i0 + lr) * D + kt + lc);
    float4 wv = *reinterpret_cast<const float4*>(W + (size_t)(j0 + lr) * D + kt + lc);
    As[lc + 0][lr] = av.x; As[lc + 1][lr] = av.y;
    As[lc + 2][lr] = av.z; As[lc + 3][lr] = av.w;
    Ws[lc + 0][lr] = wv.x; Ws[lc + 1][lr] = wv.y;
    Ws[lc + 2][lr] = wv.z; Ws[lc + 3][lr] = wv.w;
    __syncthreads();
#pragma unroll
    for (int kk = 0; kk < 16; ++kk) {
      float4 a4 = *reinterpret_cast<const float4*>(&As[kk][ty * 4]);
      float4 w4 = *reinterpret_cast<const float4*>(&Ws[kk][tx * 4]);
      float aa[4] = {a4.x, a4.y, a4.z, a4.w};
      float ww[4] = {w4.x, w4.y, w4.z, w4.w};
#pragma unroll
      for (int ii = 0; ii < 4; ++ii)
#pragma unroll
        for (int jj = 0; jj < 4; ++jj) acc[ii][jj] += aa[ii] * ww[jj];
    }
    __syncthreads();
  }
#pragma unroll
  for (int ii = 0; ii < 4; ++ii) {
    const int i = i0 + ty * 4 + ii;
    const int j = j0 + tx * 4;
    float4 cv = make_float4(acc[ii][0] + bias[j + 0], acc[ii][1] + bias[j + 1],
                            acc[ii][2] + bias[j + 2], acc[ii][3] + bias[j + 3]);
    *reinterpret_cast<float4*>(C + (size_t)i * D + j) = cv;
  }
}

// ---------------- per-head expmap0 (rows of 64), caches ||x_hyp||^2 --------
// factor = min(tanh(n), MAXN)/n, n = max(||v||, EPS); n2out = factor^2*||v||^2
__global__ __launch_bounds__(256) void expmap_heads(
    float* __restrict__ qlin, float* __restrict__ klin,
    float* __restrict__ qn2, float* __restrict__ kn2) {
  float* base = blockIdx.y ? klin : qlin;
  float* n2o = blockIdx.y ? kn2 : qn2;
  const int r = blockIdx.x * 4 + (threadIdx.x >> 6);  // (b*S+s)*H + h
  const int lane = threadIdx.x & 63;
  const size_t idx = (size_t)r * 64 + lane;
  float x = base[idx];
  float n2 = waveSum(x * x);
  float n = fmaxf(sqrtf(n2), EPSF);
  float fac = fminf(tanhf(n), MAXN) / n;
  base[idx] = x * fac;
  if (lane == 0) n2o[r] = fac * fac * n2;
}

// ---------------- pairwise hyperbolic scores -------------------------------
// score(i,j) = -0.125 * log((1+r)/(1-r)),
// r = clamp(sqrt((qi2-2t+kj2)/max(1-2t+qi2*kj2, EPS)), EPS, MAXN), t=<qi,kj>
__global__ __launch_bounds__(256) void pair_scores(
    const float* __restrict__ qh, const float* __restrict__ kh,
    const float* __restrict__ qn2, const float* __restrict__ kn2,
    float* __restrict__ sc) {
  const int bh = blockIdx.z, b = bh >> 3, h = bh & 7;
  const int i0 = blockIdx.y * 32, j0 = blockIdx.x * 32;
  __shared__ float Qs[32][68], Ks[32][68];  // +4 pad: conflict-free b128 reads
  __shared__ float qn[32], kn[32];
  const int tid = threadIdx.x;
  {
    const int lr = tid >> 3, lc = (tid & 7) * 8;
    const float* qp = qh + (size_t)(b * S + i0 + lr) * D + h * 64 + lc;
    const float* kp = kh + (size_t)(b * S + j0 + lr) * D + h * 64 + lc;
    float4 q0 = *(const float4*)qp, q1 = *(const float4*)(qp + 4);
    float4 k0 = *(const float4*)kp, k1 = *(const float4*)(kp + 4);
    *(float4*)&Qs[lr][lc] = q0; *(float4*)&Qs[lr][lc + 4] = q1;
    *(float4*)&Ks[lr][lc] = k0; *(float4*)&Ks[lr][lc + 4] = k1;
    if (tid < 32) qn[tid] = qn2[(size_t)(b * S + i0 + tid) * H + h];
    else if (tid < 64) kn[tid - 32] = kn2[(size_t)(b * S + j0 + tid - 32) * H + h];
  }
  __syncthreads();
  const int il = tid >> 3, jl = tid & 7;  // thread does (il, jl + 8c), c=0..3
  float acc[4] = {};
  for (int d0 = 0; d0 < 64; d0 += 4) {
    float4 q4 = *(const float4*)&Qs[il][d0];
#pragma unroll
    for (int c = 0; c < 4; ++c) {
      float4 k4 = *(const float4*)&Ks[jl + 8 * c][d0];
      acc[c] += q4.x * k4.x + q4.y * k4.y + q4.z * k4.z + q4.w * k4.w;
    }
  }
  const float qq = qn[il];
  float* outp = sc + ((size_t)bh * S + i0 + il) * S + j0 + jl;
#pragma unroll
  for (int c = 0; c < 4; ++c) {
    float kk2 = kn[jl + 8 * c];
    float t = acc[c];
    float num = fmaxf(qq - 2.f * t + kk2, 0.f);
    float den = fmaxf(1.f - 2.f * t + qq * kk2, EPSF);
    float r = sqrtf(num / den);
    r = fminf(fmaxf(r, EPSF), MAXN);
    outp[8 * c] = -0.125f * __logf((1.f + r) / (1.f - r));
  }
}

// ---------------- softmax over rows of 512 (one wave per row) --------------
__global__ __launch_bounds__(256) void softmax_rows(float* __restrict__ sc) {
  const int r = blockIdx.x * 4 + (threadIdx.x >> 6);
  const int lane = threadIdx.x & 63;
  float* row = sc + (size_t)r * 512 + lane * 8;
  float4 a = *(float4*)row, b4 = *(float4*)(row + 4);
  float v[8] = {a.x, a.y, a.z, a.w, b4.x, b4.y, b4.z, b4.w};
  float m = v[0];
#pragma unroll
  for (int i = 1; i < 8; ++i) m = fmaxf(m, v[i]);
  m = waveMax(m);
  float s = 0.f;
#pragma unroll
  for (int i = 0; i < 8; ++i) { v[i] = __expf(v[i] - m); s += v[i]; }
  s = waveSum(s);
  float inv = 1.0f / s;
#pragma unroll
  for (int i = 0; i < 8; ++i) v[i] *= inv;
  *(float4*)row = make_float4(v[0], v[1], v[2], v[3]);
  *(float4*)(row + 4) = make_float4(v[4], v[5], v[6], v[7]);
}

// ---------------- ctx = attn @ V per (b,h): (512x512)@(512x64) -------------
__global__ __launch_bounds__(256) void attn_v(
    const float* __restrict__ sc, const float* __restrict__ vlin,
    float* __restrict__ ctx) {
  const int bh = blockIdx.y, b = bh >> 3, h = bh & 7;
  const int i0 = blockIdx.x * 64;
  const float* P = sc + (size_t)bh * S * S;
  const float* V = vlin + (size_t)b * S * D + h * 64;
  __shared__ float Ps[32][64];  // k-major
  __shared__ float Vs[32][64];
  const int tid = threadIdx.x;
  const int tx = tid & 15, ty = tid >> 4;
  float acc[4][4] = {};
  for (int kt = 0; kt < S; kt += 32) {
    {
      const int pr = tid >> 2, pc = (tid & 3) * 8;  // P tile 64 x 32
      const float* pp = P + (size_t)(i0 + pr) * S + kt + pc;
      float4 p0 = *(const float4*)pp, p1 = *(const float4*)(pp + 4);
      Ps[pc + 0][pr] = p0.x; Ps[pc + 1][pr] = p0.y;
      Ps[pc + 2][pr] = p0.z; Ps[pc + 3][pr] = p0.w;
      Ps[pc + 4][pr] = p1.x; Ps[pc + 5][pr] = p1.y;
      Ps[pc + 6][pr] = p1.z; Ps[pc + 7][pr] = p1.w;
      const int vr = tid >> 3, vc = (tid & 7) * 8;  // V tile 32 x 64
      const float* vp = V + (size_t)(kt + vr) * D + vc;
      float4 v0 = *(const float4*)vp, v1 = *(const float4*)(vp + 4);
      *(float4*)&Vs[vr][vc] = v0;
      *(float4*)&Vs[vr][vc + 4] = v1;
    }
    __syncthreads();
#pragma unroll
    for (int kk = 0; kk < 32; ++kk) {
      float4 a4 = *(const float4*)&Ps[kk][ty * 4];
      float4 w4 = *(const float4*)&Vs[kk][tx * 4];
      float aa[4] = {a4.x, a4.y, a4.z, a4.w};
      float ww[4] = {w4.x, w4.y, w4.z, w4.w};
#pragma unroll
      for (int ii = 0; ii < 4; ++ii)
#pragma unroll
        for (int jj = 0; jj < 4; ++jj) acc[ii][jj] += aa[ii] * ww[jj];
    }
    __syncthreads();
  }
  float* Co = ctx + (size_t)b * S * D + h * 64;
#pragma unroll
  for (int ii = 0; ii < 4; ++ii) {
    const int i = i0 + ty * 4 + ii;
    float4 cv = make_float4(acc[ii][0], acc[ii][1], acc[ii][2], acc[ii][3]);
    *reinterpret_cast<float4*>(Co + (size_t)i * D + tx * 4) = cv;
  }
}

// ---------------- final expmap0 over full rows (512) -> d_out --------------
__global__ __launch_bounds__(256) void expmap_rows_full(
    const float* __restrict__ in, float* __restrict__ out) {
  const float* x = in + (size_t)blockIdx.x * D;
  float s = 0.f;
  for (int i = threadIdx.x; i < D; i += 256) { float t = x[i]; s += t * t; }
  __shared__ float sh[4];
  float wsum = waveSum(s);
  if ((threadIdx.x & 63) == 0) sh[threadIdx.x >> 6] = wsum;
  __syncthreads();
  float tot = sh[0] + sh[1] + sh[2] + sh[3];
  float n = fmaxf(sqrtf(tot), EPSF);
  float fac = fminf(tanhf(n), MAXN) / n;
  float* o = out + (size_t)blockIdx.x * D;
  for (int i = threadIdx.x; i < D; i += 256) o[i] = x[i] * fac;
}

}  // namespace

extern "C" void kernel_launch(void* const* d_in, const int* in_sizes, int n_in,
                              void* d_out, int out_size, void* d_ws,
                              size_t ws_size, hipStream_t stream) {
  const float* q = (const float*)d_in[0];
  const float* k = (const float*)d_in[1];
  const float* v = (const float*)d_in[2];
  const float* Wq = (const float*)d_in[3];
  const float* bq = (const float*)d_in[4];
  const float* Wk = (const float*)d_in[5];
  const float* bk = (const float*)d_in[6];
  const float* Wv = (const float*)d_in[7];
  const float* bv = (const float*)d_in[8];
  const float* Wo = (const float*)d_in[9];
  const float* bo = (const float*)d_in[10];
  float* out = (float*)d_out;

  float* ws = (float*)d_ws;
  const size_t NR = (size_t)BS * D;  // 524288 floats per (B,S,D) tensor
  float* tanb = ws;                  // q_tan | k_tan | v_tan   (3*NR)
  float* linb = tanb + 3 * NR;       // q_lin | k_lin | v_lin   (3*NR)
  float* qn2 = linb + 3 * NR;        // B*S*H
  float* kn2 = qn2 + (size_t)B * S * H;
  float* sc = kn2 + (size_t)B * S * H;  // B*H*S*S
  float* ctx = sc + (size_t)B * H * S * S;  // NR
  float* olin = ctx + NR;                   // NR

  logmap_rows<<<dim3(BS, 3), 256, 0, stream>>>(q, k, v, tanb);
  gemm_at_bias3<<<dim3(D / 64, BS / 64, 3), 256, 0, stream>>>(
      tanb, Wq, Wk, Wv, bq, bk, bv, linb);
  expmap_heads<<<dim3(BS * H / 4, 2), 256, 0, stream>>>(linb, linb + NR, qn2, kn2);
  pair_scores<<<dim3(S / 32, S / 32, B * H), 256, 0, stream>>>(
      linb, linb + NR, qn2, kn2, sc);
  softmax_rows<<<dim3(B * H * S / 4), 256, 0, stream>>>(sc);
  attn_v<<<dim3(S / 64, B * H), 256, 0, stream>>>(sc, linb + 2 * NR, ctx);
  gemm_at_bias3<<<dim3(D / 64, BS / 64, 1), 256, 0, stream>>>(
      ctx, Wo, Wo, Wo, bo, bo, bo, olin);
  expmap_rows_full<<<dim3(BS), 256, 0, stream>>>(olin, out);
}

// Round 2
// 59.527 us; speedup vs baseline: 2.2207x; 2.2207x over previous
//
#include <hip/hip_runtime.h>
#include <cmath>

#define DEV static __device__ __forceinline__

namespace {

constexpr int B = 2, S = 512, D = 512, H = 8;  // dh = 64
constexpr int BS = B * S;                      // 1024 token rows
constexpr float EPSF = 1e-5f;
constexpr float MAXN = 1.0f - 1e-3f;           // MAX_NORM / sqrt(c)

typedef unsigned short u16;
typedef unsigned int u32;
typedef __attribute__((ext_vector_type(8))) short bf8_t;      // 8 bf16 (16B)
typedef __attribute__((ext_vector_type(8))) _Float16 h8_t;    // 8 f16 (16B)
typedef __attribute__((ext_vector_type(4))) float f4_t;

DEV float waveSum(float v) {
#pragma unroll
  for (int o = 32; o > 0; o >>= 1) v += __shfl_xor(v, o, 64);
  return v;
}
DEV float waveMax(float v) {
#pragma unroll
  for (int o = 32; o > 0; o >>= 1) v = fmaxf(v, __shfl_xor(v, o, 64));
  return v;
}

DEV u16 f2bf(float f) {  // RNE bf16 (finite inputs)
  u32 x = __float_as_uint(f);
  u32 r = x + 0x7fffu + ((x >> 16) & 1u);
  return (u16)(r >> 16);
}
DEV float bf2f(u16 u) { return __uint_as_float(((u32)u) << 16); }

// ---------------- logmap0 over full rows (512) -> bf16 ---------------------
__global__ __launch_bounds__(256) void logmap_rows_bf16(
    const float* __restrict__ q, const float* __restrict__ k,
    const float* __restrict__ v, u16* __restrict__ outb) {
  const float* in = blockIdx.y == 0 ? q : (blockIdx.y == 1 ? k : v);
  u16* out = outb + (size_t)blockIdx.y * BS * D;
  const int row = blockIdx.x;
  const float2 xv = *(const float2*)(in + (size_t)row * D + threadIdx.x * 2);
  float s = xv.x * xv.x + xv.y * xv.y;
  __shared__ float sh[4];
  float ws = waveSum(s);
  if ((threadIdx.x & 63) == 0) sh[threadIdx.x >> 6] = ws;
  __syncthreads();
  float tot = sh[0] + sh[1] + sh[2] + sh[3];
  float n = fmaxf(sqrtf(tot), EPSF);
  float z = fminf(n, 1.0f - EPSF);
  float fac = 0.5f * __logf((1.0f + z) / (1.0f - z)) / n;  // artanh(z)/n
  ushort2 o;
  o.x = f2bf(xv.x * fac);
  o.y = f2bf(xv.y * fac);
  *(ushort2*)(out + (size_t)row * D + threadIdx.x * 2) = o;
}

// ---------------- convert 4 weight matrices fp32 -> bf16 -------------------
__global__ __launch_bounds__(256) void conv_w(
    const float* __restrict__ Wq, const float* __restrict__ Wk,
    const float* __restrict__ Wv, const float* __restrict__ Wo,
    u16* __restrict__ out) {
  const int z = blockIdx.y;
  const float* Wsel = z == 0 ? Wq : (z == 1 ? Wk : (z == 2 ? Wv : Wo));
  const int idx = (blockIdx.x * 256 + threadIdx.x) * 4;
  float4 v = *(const float4*)(Wsel + idx);
  ushort4 o;
  o.x = f2bf(v.x); o.y = f2bf(v.y); o.z = f2bf(v.z); o.w = f2bf(v.w);
  *(ushort4*)(out + (size_t)z * D * D + idx) = o;
}

// ---------------- C = A @ W^T + bias, bf16 MFMA ----------------------------
// A: [BS][512] bf16 (slab z), W: [512][512] bf16 (slab z), C: fp32 (slab z).
// 64x64 tile, BK=64, 4 waves: wave w does rows w*16..w*16+15 x 64 cols.
__global__ __launch_bounds__(256) void gemm_mfma_bf16(
    const u16* __restrict__ Abase, const u16* __restrict__ Wbase,
    const float* __restrict__ b0, const float* __restrict__ b1,
    const float* __restrict__ b2, float* __restrict__ Cbase) {
  const int z = blockIdx.z;
  const u16* A = Abase + (size_t)z * BS * D;
  const u16* W = Wbase + (size_t)z * D * D;
  const float* bias = z == 0 ? b0 : (z == 1 ? b1 : b2);
  float* C = Cbase + (size_t)z * BS * D;
  const int i0 = blockIdx.y * 64, j0 = blockIdx.x * 64;
  __shared__ __align__(16) u16 As[64 * 64], Bs[64 * 64];
  const int tid = threadIdx.x;
  const int w = tid >> 6, l = tid & 63, lg = l >> 4, lr = l & 15;
  const int srow = tid >> 3, scb = tid & 7;
  f4_t acc[4] = {{0, 0, 0, 0}, {0, 0, 0, 0}, {0, 0, 0, 0}, {0, 0, 0, 0}};
  for (int kt = 0; kt < D; kt += 64) {
    bf8_t a0 = *(const bf8_t*)(A + (size_t)(i0 + srow) * D + kt + scb * 8);
    bf8_t a1 = *(const bf8_t*)(A + (size_t)(i0 + srow + 32) * D + kt + scb * 8);
    bf8_t w0 = *(const bf8_t*)(W + (size_t)(j0 + srow) * D + kt + scb * 8);
    bf8_t w1 = *(const bf8_t*)(W + (size_t)(j0 + srow + 32) * D + kt + scb * 8);
    __syncthreads();  // protect previous iteration's frag reads
    const int sw = 8 * (scb ^ (srow & 7));
    *(bf8_t*)&As[srow * 64 + sw] = a0;
    *(bf8_t*)&As[(srow + 32) * 64 + sw] = a1;  // (srow+32)&7 == srow&7
    *(bf8_t*)&Bs[srow * 64 + sw] = w0;
    *(bf8_t*)&Bs[(srow + 32) * 64 + sw] = w1;
    __syncthreads();
#pragma unroll
    for (int ks = 0; ks < 2; ++ks) {
      const int arow = w * 16 + lr;
      bf8_t af = *(const bf8_t*)&As[arow * 64 + 8 * ((ks * 4 + lg) ^ (arow & 7))];
#pragma unroll
      for (int nf = 0; nf < 4; ++nf) {
        const int brow = nf * 16 + lr;
        bf8_t bfr = *(const bf8_t*)&Bs[brow * 64 + 8 * ((ks * 4 + lg) ^ (brow & 7))];
        acc[nf] = __builtin_amdgcn_mfma_f32_16x16x32_bf16(af, bfr, acc[nf], 0, 0, 0);
      }
    }
  }
#pragma unroll
  for (int nf = 0; nf < 4; ++nf) {
    const int j = j0 + nf * 16 + lr;
    const float bb = bias[j];
#pragma unroll
    for (int r = 0; r < 4; ++r) {
      const int i = i0 + w * 16 + lg * 4 + r;
      C[(size_t)i * D + j] = acc[nf][r] + bb;
    }
  }
}

// ---------------- per-head expmap0 + caches + V transpose ------------------
// y=0: q expmap -> bf16 + qn2; y=1: k expmap -> bf16 + kn2;
// y=2: v convert fp32 -> f16, transposed to vT[bh*64+d][s].
__global__ __launch_bounds__(256) void expmap_heads_v2(
    const float* __restrict__ lin, u16* __restrict__ hq, u16* __restrict__ hk,
    _Float16* __restrict__ vT, float* __restrict__ qn2,
    float* __restrict__ kn2) {
  const int y = blockIdx.y;
  const int hr = blockIdx.x * 4 + (threadIdx.x >> 6);  // t*H + h, 0..8191
  const int l = threadIdx.x & 63;
  const float* src = lin + (size_t)y * BS * D;
  const size_t idx = (size_t)hr * 64 + l;  // == t*512 + h*64 + l
  float x = src[idx];
  if (y == 2) {
    const int t = hr >> 3, h = hr & 7;
    const int b = t >> 9, s = t & 511;
    vT[((size_t)((b * 8 + h) * 64) + l) * 512 + s] = (_Float16)x;
    return;
  }
  float n2 = waveSum(x * x);
  float n = fmaxf(sqrtf(n2), EPSF);
  float fac = fminf(tanhf(n), MAXN) / n;
  u16 xr = f2bf(x * fac);
  float xf = bf2f(xr);
  float n2r = waveSum(xf * xf);  // norm^2 of the *rounded* point
  (y == 0 ? hq : hk)[idx] = xr;
  if (l == 0) (y == 0 ? qn2 : kn2)[hr] = n2r;
}

// ---------------- pairwise hyperbolic scores via MFMA ----------------------
// score(i,j) = -0.25*artanh(r), r = clamp(sqrt(num/den), EPS, MAXN),
// num = qq - 2t + kk, den = max(1 - 2t + qq*kk, EPS), t = <q_i, k_j>.
__global__ __launch_bounds__(256) void pair_scores_mfma(
    const u16* __restrict__ qh, const u16* __restrict__ kh,
    const float* __restrict__ qn2, const float* __restrict__ kn2,
    _Float16* __restrict__ sc) {
  const int bh = blockIdx.z, b = bh >> 3, h = bh & 7;
  const int i0 = blockIdx.y * 64, j0 = blockIdx.x * 64;
  __shared__ __align__(16) u16 Qs[64 * 64], Ks[64 * 64];
  __shared__ float qn[64], kn[64];
  const int tid = threadIdx.x;
  const int w = tid >> 6, l = tid & 63, lg = l >> 4, lr = l & 15;
  const int srow = tid >> 3, scb = tid & 7;
  {
    const u16* qp = qh + (size_t)(b * S + i0 + srow) * D + h * 64 + scb * 8;
    const u16* kp = kh + (size_t)(b * S + j0 + srow) * D + h * 64 + scb * 8;
    bf8_t q0 = *(const bf8_t*)qp;
    bf8_t q1 = *(const bf8_t*)(qp + (size_t)32 * D);
    bf8_t k0 = *(const bf8_t*)kp;
    bf8_t k1 = *(const bf8_t*)(kp + (size_t)32 * D);
    const int sw = 8 * (scb ^ (srow & 7));
    *(bf8_t*)&Qs[srow * 64 + sw] = q0;
    *(bf8_t*)&Qs[(srow + 32) * 64 + sw] = q1;
    *(bf8_t*)&Ks[srow * 64 + sw] = k0;
    *(bf8_t*)&Ks[(srow + 32) * 64 + sw] = k1;
    if (tid < 64) qn[tid] = qn2[(size_t)(b * S + i0 + tid) * H + h];
    else if (tid < 128) kn[tid - 64] = kn2[(size_t)(b * S + j0 + tid - 64) * H + h];
  }
  __syncthreads();
  f4_t acc[4] = {{0, 0, 0, 0}, {0, 0, 0, 0}, {0, 0, 0, 0}, {0, 0, 0, 0}};
#pragma unroll
  for (int ks = 0; ks < 2; ++ks) {
    const int arow = w * 16 + lr;
    bf8_t af = *(const bf8_t*)&Qs[arow * 64 + 8 * ((ks * 4 + lg) ^ (arow & 7))];
#pragma unroll
    for (int nf = 0; nf < 4; ++nf) {
      const int brow = nf * 16 + lr;
      bf8_t bfr = *(const bf8_t*)&Ks[brow * 64 + 8 * ((ks * 4 + lg) ^ (brow & 7))];
      acc[nf] = __builtin_amdgcn_mfma_f32_16x16x32_bf16(af, bfr, acc[nf], 0, 0, 0);
    }
  }
  const int ilb = w * 16 + lg * 4;
#pragma unroll
  for (int nf = 0; nf < 4; ++nf) {
    const int jl = nf * 16 + lr;
    const float kk = kn[jl];
#pragma unroll
    for (int r = 0; r < 4; ++r) {
      const float qq = qn[ilb + r];
      const float t = acc[nf][r];
      float num = fmaxf(qq - 2.f * t + kk, 0.f);
      float den = fmaxf(1.f - 2.f * t + qq * kk, EPSF);
      float rr = sqrtf(num / den);
      rr = fminf(fmaxf(rr, EPSF), MAXN);
      float s = -0.125f * __logf((1.f + rr) / (1.f - rr));
      sc[((size_t)bh * S + i0 + ilb + r) * S + j0 + jl] = (_Float16)s;
    }
  }
}

// ---------------- softmax over rows of 512, in-place on f16 ----------------
__global__ __launch_bounds__(256) void softmax_half(_Float16* __restrict__ sc) {
  const size_t r = blockIdx.x * 4 + (threadIdx.x >> 6);
  const int l = threadIdx.x & 63;
  _Float16* row = sc + r * 512 + l * 8;
  h8_t v = *(const h8_t*)row;
  float f[8];
#pragma unroll
  for (int i = 0; i < 8; ++i) f[i] = (float)v[i];
  float m = f[0];
#pragma unroll
  for (int i = 1; i < 8; ++i) m = fmaxf(m, f[i]);
  m = waveMax(m);
  float s = 0.f;
#pragma unroll
  for (int i = 0; i < 8; ++i) { f[i] = __expf(f[i] - m); s += f[i]; }
  s = waveSum(s);
  float inv = 1.0f / s;
  h8_t o;
#pragma unroll
  for (int i = 0; i < 8; ++i) o[i] = (_Float16)(f[i] * inv);
  *(h8_t*)row = o;
}

// ---------------- ctx = P @ V via f16 MFMA, out bf16 -----------------------
// P: [bh][512][512] f16, vT: [bh][64][512] f16 -> ctx bf16 [B*S][512].
__global__ __launch_bounds__(256) void attn_v_mfma(
    const _Float16* __restrict__ P, const _Float16* __restrict__ vT,
    u16* __restrict__ ctx) {
  const int bh = blockIdx.y, b = bh >> 3, h = bh & 7;
  const int i0 = blockIdx.x * 64;
  __shared__ __align__(16) _Float16 Ps[64 * 64], Vs[64 * 64];
  const int tid = threadIdx.x;
  const int w = tid >> 6, l = tid & 63, lg = l >> 4, lr = l & 15;
  const int srow = tid >> 3, scb = tid & 7;
  f4_t acc[4] = {{0, 0, 0, 0}, {0, 0, 0, 0}, {0, 0, 0, 0}, {0, 0, 0, 0}};
  for (int kt = 0; kt < S; kt += 64) {
    h8_t p0 = *(const h8_t*)(P + ((size_t)bh * S + i0 + srow) * S + kt + scb * 8);
    h8_t p1 = *(const h8_t*)(P + ((size_t)bh * S + i0 + srow + 32) * S + kt + scb * 8);
    h8_t v0 = *(const h8_t*)(vT + ((size_t)bh * 64 + srow) * S + kt + scb * 8);
    h8_t v1 = *(const h8_t*)(vT + ((size_t)bh * 64 + srow + 32) * S + kt + scb * 8);
    __syncthreads();
    const int sw = 8 * (scb ^ (srow & 7));
    *(h8_t*)&Ps[srow * 64 + sw] = p0;
    *(h8_t*)&Ps[(srow + 32) * 64 + sw] = p1;
    *(h8_t*)&Vs[srow * 64 + sw] = v0;
    *(h8_t*)&Vs[(srow + 32) * 64 + sw] = v1;
    __syncthreads();
#pragma unroll
    for (int ks = 0; ks < 2; ++ks) {
      const int arow = w * 16 + lr;
      h8_t af = *(const h8_t*)&Ps[arow * 64 + 8 * ((ks * 4 + lg) ^ (arow & 7))];
#pragma unroll
      for (int nf = 0; nf < 4; ++nf) {
        const int brow = nf * 16 + lr;
        h8_t bfr = *(const h8_t*)&Vs[brow * 64 + 8 * ((ks * 4 + lg) ^ (brow & 7))];
        acc[nf] = __builtin_amdgcn_mfma_f32_16x16x32_f16(af, bfr, acc[nf], 0, 0, 0);
      }
    }
  }
#pragma unroll
  for (int nf = 0; nf < 4; ++nf) {
    const int n = nf * 16 + lr;
#pragma unroll
    for (int r = 0; r < 4; ++r) {
      const int i = i0 + w * 16 + lg * 4 + r;
      ctx[(size_t)(b * S + i) * D + h * 64 + n] = f2bf(acc[nf][r]);
    }
  }
}

// ---------------- final expmap0 over full rows (512) -> d_out --------------
__global__ __launch_bounds__(256) void expmap_rows_full(
    const float* __restrict__ in, float* __restrict__ out) {
  const float* x = in + (size_t)blockIdx.x * D;
  float s = 0.f;
  for (int i = threadIdx.x; i < D; i += 256) { float t = x[i]; s += t * t; }
  __shared__ float sh[4];
  float ws = waveSum(s);
  if ((threadIdx.x & 63) == 0) sh[threadIdx.x >> 6] = ws;
  __syncthreads();
  float tot = sh[0] + sh[1] + sh[2] + sh[3];
  float n = fmaxf(sqrtf(tot), EPSF);
  float fac = fminf(tanhf(n), MAXN) / n;
  float* o = out + (size_t)blockIdx.x * D;
  for (int i = threadIdx.x; i < D; i += 256) o[i] = x[i] * fac;
}

}  // namespace

extern "C" void kernel_launch(void* const* d_in, const int* in_sizes, int n_in,
                              void* d_out, int out_size, void* d_ws,
                              size_t ws_size, hipStream_t stream) {
  const float* q = (const float*)d_in[0];
  const float* k = (const float*)d_in[1];
  const float* v = (const float*)d_in[2];
  const float* Wq = (const float*)d_in[3];
  const float* bq = (const float*)d_in[4];
  const float* Wk = (const float*)d_in[5];
  const float* bk = (const float*)d_in[6];
  const float* Wv = (const float*)d_in[7];
  const float* bv = (const float*)d_in[8];
  const float* Wo = (const float*)d_in[9];
  const float* bo = (const float*)d_in[10];
  float* out = (float*)d_out;

  char* w8 = (char*)d_ws;
  u16* tanb = (u16*)(w8 + 0);                // 3 MB  (q|k|v tangent, bf16)
  u16* Wbf = (u16*)(w8 + 3145728);           // 2 MB  (Wq|Wk|Wv|Wo, bf16)
  float* linb = (float*)(w8 + 5242880);      // 6 MB  (q|k|v projected, fp32)
  u16* hypq = (u16*)(w8 + 11534336);         // 1 MB
  u16* hypk = (u16*)(w8 + 12582912);         // 1 MB
  _Float16* vT = (_Float16*)(w8 + 13631488); // 1 MB  ([bh][64][512] f16)
  float* qn2 = (float*)(w8 + 14680064);      // 32 KB
  float* kn2 = (float*)(w8 + 14712832);      // 32 KB
  _Float16* sc = (_Float16*)(w8 + 14745600); // 8 MB  (scores/P, f16)
  u16* ctx = (u16*)(w8 + 5242880);           // reuse linb[0:1MB) (dead)
  float* olin = (float*)(w8 + 7340032);      // reuse linb+2MB (2 MB)

  logmap_rows_bf16<<<dim3(BS, 3), 256, 0, stream>>>(q, k, v, tanb);
  conv_w<<<dim3(256, 4), 256, 0, stream>>>(Wq, Wk, Wv, Wo, Wbf);
  gemm_mfma_bf16<<<dim3(8, 16, 3), 256, 0, stream>>>(tanb, Wbf, bq, bk, bv, linb);
  expmap_heads_v2<<<dim3(2048, 3), 256, 0, stream>>>(linb, hypq, hypk, vT, qn2, kn2);
  pair_scores_mfma<<<dim3(8, 8, 16), 256, 0, stream>>>(hypq, hypk, qn2, kn2, sc);
  softmax_half<<<dim3(2048), 256, 0, stream>>>(sc);
  attn_v_mfma<<<dim3(8, 16), 256, 0, stream>>>(sc, vT, ctx);
  gemm_mfma_bf16<<<dim3(8, 16, 1), 256, 0, stream>>>(ctx, Wbf + 3 * D * D, bo, bo, bo, olin);
  expmap_rows_full<<<dim3(BS), 256, 0, stream>>>(olin, out);
}

// Round 4
// 55.978 us; speedup vs baseline: 2.3615x; 1.0634x over previous
//
#include <hip/hip_runtime.h>
#include <cmath>

#define DEV static __device__ __forceinline__

namespace {

constexpr int B = 2, S = 512, D = 512, H = 8;  // dh = 64
constexpr int BS = B * S;                      // 1024 token rows
constexpr float EPSF = 1e-5f;
constexpr float MAXN = 1.0f - 1e-3f;           // MAX_NORM / sqrt(c)

typedef unsigned short u16;
typedef unsigned int u32;
typedef __attribute__((ext_vector_type(8))) short bf8_t;    // 16B mover / bf16x8
typedef __attribute__((ext_vector_type(8))) _Float16 h8_t;  // f16x8
typedef __attribute__((ext_vector_type(4))) float f4_t;

DEV float waveSum(float v) {
#pragma unroll
  for (int o = 32; o > 0; o >>= 1) v += __shfl_xor(v, o, 64);
  return v;
}

DEV u16 f2bf(float f) {  // RNE bf16
  u32 x = __float_as_uint(f);
  u32 r = x + 0x7fffu + ((x >> 16) & 1u);
  return (u16)(r >> 16);
}
DEV float bf2f(u16 u) { return __uint_as_float(((u32)u) << 16); }
DEV u16 f2h(float f) {
  _Float16 h = (_Float16)f;
  u16 u;
  __builtin_memcpy(&u, &h, 2);
  return u;
}
DEV float tanh_pos(float n) {  // tanh for n >= 0
  float e = __builtin_amdgcn_exp2f(2.8853900817779268f * n);  // e^(2n)
  return (e - 1.f) / (e + 1.f);
}

// ---------------- prep: logmap0 rows (y=0..2) + weight bf16 conv (y=3) -----
__global__ __launch_bounds__(256) void prep(
    const float* __restrict__ q, const float* __restrict__ k,
    const float* __restrict__ v, const float* __restrict__ Wq,
    const float* __restrict__ Wk, const float* __restrict__ Wv,
    const float* __restrict__ Wo, u16* __restrict__ tanb,
    u16* __restrict__ Wbf) {
  const int y = blockIdx.y;
  if (y == 3) {
    const int x = blockIdx.x;  // 0..1023 -> 4 matrices x 256 blocks
    const int wi = x >> 8;
    const float* Wsel = wi == 0 ? Wq : (wi == 1 ? Wk : (wi == 2 ? Wv : Wo));
    const int idx = ((x & 255) * 256 + threadIdx.x) * 4;
    float4 val = *(const float4*)(Wsel + idx);
    ushort4 o;
    o.x = f2bf(val.x); o.y = f2bf(val.y); o.z = f2bf(val.z); o.w = f2bf(val.w);
    *(ushort4*)(Wbf + (size_t)wi * D * D + idx) = o;
    return;
  }
  const float* in = y == 0 ? q : (y == 1 ? k : v);
  u16* out = tanb + (size_t)y * BS * D;
  const int row = blockIdx.x;
  const float2 xv = *(const float2*)(in + (size_t)row * D + threadIdx.x * 2);
  float s = xv.x * xv.x + xv.y * xv.y;
  __shared__ float sh[4];
  float ws = waveSum(s);
  if ((threadIdx.x & 63) == 0) sh[threadIdx.x >> 6] = ws;
  __syncthreads();
  float tot = sh[0] + sh[1] + sh[2] + sh[3];
  float n = fmaxf(sqrtf(tot), EPSF);
  float z = fminf(n, 1.0f - EPSF);
  // artanh(z)/n via log2: artanh(z) = 0.5*ln((1+z)/(1-z))
  float fac = 0.34657359027997264f *
              __builtin_amdgcn_logf((1.0f + z) / (1.0f - z)) / n;
  ushort2 o;
  o.x = f2bf(xv.x * fac);
  o.y = f2bf(xv.y * fac);
  *(ushort2*)(out + (size_t)row * D + threadIdx.x * 2) = o;
}

// ---------------- QKV GEMM + fused expmap / V-transpose epilogues ----------
// z=0: q -> hq bf16 + qn2 ; z=1: k -> hk bf16 + kn2 ; z=2: v -> vT f16.
__global__ __launch_bounds__(256) void gemm_qkv(
    const u16* __restrict__ tanb, const u16* __restrict__ Wbf,
    const float* __restrict__ bq, const float* __restrict__ bk,
    const float* __restrict__ bv, u16* __restrict__ hq, u16* __restrict__ hk,
    u16* __restrict__ vT, float* __restrict__ qn2, float* __restrict__ kn2) {
  const int z = blockIdx.z;
  const u16* A = tanb + (size_t)z * BS * D;
  const u16* W = Wbf + (size_t)z * D * D;
  const float* bias = z == 0 ? bq : (z == 1 ? bk : bv);
  const int i0 = blockIdx.y * 64, j0 = blockIdx.x * 64, h = blockIdx.x;
  __shared__ __align__(16) u16 As[4096], Bs[4096];
  const int tid = threadIdx.x;
  const int w = tid >> 6, l = tid & 63, lg = l >> 4, lr = l & 15;
  const int srow = tid >> 3, scb = tid & 7;
  f4_t acc[4] = {{0, 0, 0, 0}, {0, 0, 0, 0}, {0, 0, 0, 0}, {0, 0, 0, 0}};
  for (int kt = 0; kt < D; kt += 64) {
    bf8_t a0 = *(const bf8_t*)(A + (size_t)(i0 + srow) * D + kt + scb * 8);
    bf8_t a1 = *(const bf8_t*)(A + (size_t)(i0 + srow + 32) * D + kt + scb * 8);
    bf8_t w0 = *(const bf8_t*)(W + (size_t)(j0 + srow) * D + kt + scb * 8);
    bf8_t w1 = *(const bf8_t*)(W + (size_t)(j0 + srow + 32) * D + kt + scb * 8);
    __syncthreads();
    const int sw = 8 * (scb ^ (srow & 7));
    *(bf8_t*)&As[srow * 64 + sw] = a0;
    *(bf8_t*)&As[(srow + 32) * 64 + sw] = a1;
    *(bf8_t*)&Bs[srow * 64 + sw] = w0;
    *(bf8_t*)&Bs[(srow + 32) * 64 + sw] = w1;
    __syncthreads();
#pragma unroll
    for (int ks = 0; ks < 2; ++ks) {
      const int arow = w * 16 + lr;
      bf8_t af = *(const bf8_t*)&As[arow * 64 + 8 * ((ks * 4 + lg) ^ (arow & 7))];
#pragma unroll
      for (int nf = 0; nf < 4; ++nf) {
        const int brow = nf * 16 + lr;
        bf8_t bfr = *(const bf8_t*)&Bs[brow * 64 + 8 * ((ks * 4 + lg) ^ (brow & 7))];
        acc[nf] = __builtin_amdgcn_mfma_f32_16x16x32_bf16(af, bfr, acc[nf], 0, 0, 0);
      }
    }
  }
  float c[4][4];
#pragma unroll
  for (int nf = 0; nf < 4; ++nf) {
    const float bb = bias[j0 + nf * 16 + lr];
#pragma unroll
    for (int r = 0; r < 4; ++r) c[nf][r] = acc[nf][r] + bb;
  }
  if (z < 2) {
    // per-head expmap: norm over the row's 64 cols (lr-group reduce)
    float part[4] = {0, 0, 0, 0};
#pragma unroll
    for (int nf = 0; nf < 4; ++nf)
#pragma unroll
      for (int r = 0; r < 4; ++r) part[r] += c[nf][r] * c[nf][r];
#pragma unroll
    for (int off = 1; off < 16; off <<= 1)
#pragma unroll
      for (int r = 0; r < 4; ++r) part[r] += __shfl_xor(part[r], off, 64);
    float fac[4];
#pragma unroll
    for (int r = 0; r < 4; ++r) {
      float n = fmaxf(sqrtf(part[r]), EPSF);
      fac[r] = fminf(tanh_pos(n), MAXN) / n;
    }
    u16 yb[4][4];
    float p2[4] = {0, 0, 0, 0};
#pragma unroll
    for (int nf = 0; nf < 4; ++nf)
#pragma unroll
      for (int r = 0; r < 4; ++r) {
        u16 t = f2bf(c[nf][r] * fac[r]);
        yb[nf][r] = t;
        float yf = bf2f(t);
        p2[r] += yf * yf;  // norm^2 of the rounded point
      }
#pragma unroll
    for (int off = 1; off < 16; off <<= 1)
#pragma unroll
      for (int r = 0; r < 4; ++r) p2[r] += __shfl_xor(p2[r], off, 64);
    u16* dst = z == 0 ? hq : hk;
    float* n2o = z == 0 ? qn2 : kn2;
#pragma unroll
    for (int nf = 0; nf < 4; ++nf)
#pragma unroll
      for (int r = 0; r < 4; ++r)
        dst[(size_t)(i0 + w * 16 + lg * 4 + r) * D + j0 + nf * 16 + lr] = yb[nf][r];
    if (lr == 0)
#pragma unroll
      for (int r = 0; r < 4; ++r)
        n2o[(size_t)(i0 + w * 16 + lg * 4 + r) * H + h] = p2[r];
  } else {
    // V: f16, transpose via LDS -> vT[(b*8+h)*64 + d][s]
    __syncthreads();  // all MFMA LDS reads done before reuse of As
#pragma unroll
    for (int nf = 0; nf < 4; ++nf)
#pragma unroll
      for (int r = 0; r < 4; ++r) {
        const int prow = w * 16 + lg * 4 + r;   // local token s
        const int pcol = nf * 16 + lr;          // local d
        As[prow * 64 + 8 * ((pcol >> 3) ^ (prow & 7)) + (pcol & 7)] = f2h(c[nf][r]);
      }
    __syncthreads();
    const int d = tid >> 2, s0 = (tid & 3) * 16;
    const int b = i0 >> 9, sb = (i0 & 511) + s0;
    bf8_t o0, o1;
#pragma unroll
    for (int j = 0; j < 8; ++j) {
      const int s = s0 + j;
      o0[j] = (short)As[s * 64 + 8 * ((d >> 3) ^ (s & 7)) + (d & 7)];
    }
#pragma unroll
    for (int j = 0; j < 8; ++j) {
      const int s = s0 + 8 + j;
      o1[j] = (short)As[s * 64 + 8 * ((d >> 3) ^ (s & 7)) + (d & 7)];
    }
    u16* dst = vT + ((size_t)((b * 8 + h) * 64 + d)) * S + sb;
    *(bf8_t*)dst = o0;
    *(bf8_t*)(dst + 8) = o1;
  }
}

// ---------------- fused attention: scores + exp + PV, no score buffer ------
// scores bounded in [-0.95, 0] => exp without max-subtraction is safe.
__global__ __launch_bounds__(256) void fused_attn(
    const u16* __restrict__ hq, const u16* __restrict__ hk,
    const u16* __restrict__ vT, const float* __restrict__ qn2,
    const float* __restrict__ kn2, u16* __restrict__ ctx) {
  const int bh = blockIdx.y, b = bh >> 3, h = bh & 7;
  const int i0 = blockIdx.x * 64;
  __shared__ __align__(16) u16 Ks[4096], Vt[4096], Ps[4096];
  __shared__ float knl[512];
  const int tid = threadIdx.x;
  const int w = tid >> 6, l = tid & 63, lg = l >> 4, lr = l & 15;
  // Q fragments + q norms (persistent)
  bf8_t qf[2];
#pragma unroll
  for (int ks = 0; ks < 2; ++ks)
    qf[ks] = *(const bf8_t*)(hq + (size_t)(b * S + i0 + w * 16 + lr) * D +
                             h * 64 + ks * 32 + lg * 8);
  float qq[4];
#pragma unroll
  for (int r = 0; r < 4; ++r)
    qq[r] = qn2[(size_t)(b * S + i0 + w * 16 + lg * 4 + r) * H + h];
  knl[tid] = kn2[(size_t)(b * S + tid) * H + h];
  knl[tid + 256] = kn2[(size_t)(b * S + tid + 256) * H + h];

  f4_t acc_o[4] = {{0, 0, 0, 0}, {0, 0, 0, 0}, {0, 0, 0, 0}, {0, 0, 0, 0}};
  float rsum[4] = {0, 0, 0, 0};
  const int krow = tid >> 3, kc = tid & 7;
  const int vd = tid >> 2, vc = (tid & 3) * 2;  // Vt row d, 2 chunks of 8 s

  for (int kt = 0; kt < 8; ++kt) {
    __syncthreads();  // previous tile's LDS reads done (also covers knl)
    bf8_t k0 = *(const bf8_t*)(hk + (size_t)(b * S + kt * 64 + krow) * D + h * 64 + kc * 8);
    bf8_t k1 = *(const bf8_t*)(hk + (size_t)(b * S + kt * 64 + krow + 32) * D + h * 64 + kc * 8);
    bf8_t v0 = *(const bf8_t*)(vT + ((size_t)(bh * 64 + vd)) * S + kt * 64 + vc * 8);
    bf8_t v1 = *(const bf8_t*)(vT + ((size_t)(bh * 64 + vd)) * S + kt * 64 + vc * 8 + 8);
    *(bf8_t*)&Ks[krow * 64 + 8 * (kc ^ (krow & 7))] = k0;
    *(bf8_t*)&Ks[(krow + 32) * 64 + 8 * (kc ^ (krow & 7))] = k1;
    *(bf8_t*)&Vt[vd * 64 + 8 * (vc ^ (vd & 7))] = v0;
    *(bf8_t*)&Vt[vd * 64 + 8 * ((vc + 1) ^ (vd & 7))] = v1;
    __syncthreads();
    // QK^T
    f4_t sa[4] = {{0, 0, 0, 0}, {0, 0, 0, 0}, {0, 0, 0, 0}, {0, 0, 0, 0}};
#pragma unroll
    for (int ks = 0; ks < 2; ++ks) {
#pragma unroll
      for (int nf = 0; nf < 4; ++nf) {
        const int brow = nf * 16 + lr;
        bf8_t bfr = *(const bf8_t*)&Ks[brow * 64 + 8 * ((ks * 4 + lg) ^ (brow & 7))];
        sa[nf] = __builtin_amdgcn_mfma_f32_16x16x32_bf16(qf[ks], bfr, sa[nf], 0, 0, 0);
      }
    }
    // distance transform + exp, stash P (f16) into own wave's rows
    float ps[4] = {0, 0, 0, 0};
#pragma unroll
    for (int nf = 0; nf < 4; ++nf) {
      const float kk = knl[kt * 64 + nf * 16 + lr];
#pragma unroll
      for (int r = 0; r < 4; ++r) {
        const float t = sa[nf][r];
        float num = fmaxf(qq[r] - 2.f * t + kk, 0.f);
        float den = fmaxf(1.f - 2.f * t + qq[r] * kk, EPSF);
        float rr = fminf(fmaxf(sqrtf(num / den), EPSF), MAXN);
        // p = exp(-0.125*ln((1+r)/(1-r))) = ((1-r)/(1+r))^(1/8)
        float p = __builtin_amdgcn_exp2f(
            0.125f * __builtin_amdgcn_logf((1.f - rr) / (1.f + rr)));
        ps[r] += p;
        const int prow = w * 16 + lg * 4 + r, pcol = nf * 16 + lr;
        Ps[prow * 64 + 8 * ((pcol >> 3) ^ (prow & 7)) + (pcol & 7)] = f2h(p);
      }
    }
#pragma unroll
    for (int off = 1; off < 16; off <<= 1)
#pragma unroll
      for (int r = 0; r < 4; ++r) ps[r] += __shfl_xor(ps[r], off, 64);
#pragma unroll
    for (int r = 0; r < 4; ++r) rsum[r] += ps[r];
    // PV (same-wave P rows: LDS in-order per wave, no barrier needed)
#pragma unroll
    for (int ks = 0; ks < 2; ++ks) {
      const int arow = w * 16 + lr;
      h8_t pa = *(const h8_t*)&Ps[arow * 64 + 8 * ((ks * 4 + lg) ^ (arow & 7))];
#pragma unroll
      for (int nf = 0; nf < 4; ++nf) {
        const int brow = nf * 16 + lr;
        h8_t vb = *(const h8_t*)&Vt[brow * 64 + 8 * ((ks * 4 + lg) ^ (brow & 7))];
        acc_o[nf] = __builtin_amdgcn_mfma_f32_16x16x32_f16(pa, vb, acc_o[nf], 0, 0, 0);
      }
    }
  }
  float inv[4];
#pragma unroll
  for (int r = 0; r < 4; ++r) inv[r] = 1.f / rsum[r];
#pragma unroll
  for (int nf = 0; nf < 4; ++nf)
#pragma unroll
    for (int r = 0; r < 4; ++r)
      ctx[(size_t)(b * S + i0 + w * 16 + lg * 4 + r) * D + h * 64 + nf * 16 + lr] =
          f2bf(acc_o[nf][r] * inv[r]);
}

// ---------------- out projection: ctx @ Wo^T + bo -> fp32 ------------------
__global__ __launch_bounds__(256) void gemm_out(
    const u16* __restrict__ A, const u16* __restrict__ W,
    const float* __restrict__ bias, float* __restrict__ C) {
  const int i0 = blockIdx.y * 64, j0 = blockIdx.x * 64;
  __shared__ __align__(16) u16 As[4096], Bs[4096];
  const int tid = threadIdx.x;
  const int w = tid >> 6, l = tid & 63, lg = l >> 4, lr = l & 15;
  const int srow = tid >> 3, scb = tid & 7;
  f4_t acc[4] = {{0, 0, 0, 0}, {0, 0, 0, 0}, {0, 0, 0, 0}, {0, 0, 0, 0}};
  for (int kt = 0; kt < D; kt += 64) {
    bf8_t a0 = *(const bf8_t*)(A + (size_t)(i0 + srow) * D + kt + scb * 8);
    bf8_t a1 = *(const bf8_t*)(A + (size_t)(i0 + srow + 32) * D + kt + scb * 8);
    bf8_t w0 = *(const bf8_t*)(W + (size_t)(j0 + srow) * D + kt + scb * 8);
    bf8_t w1 = *(const bf8_t*)(W + (size_t)(j0 + srow + 32) * D + kt + scb * 8);
    __syncthreads();
    const int sw = 8 * (scb ^ (srow & 7));
    *(bf8_t*)&As[srow * 64 + sw] = a0;
    *(bf8_t*)&As[(srow + 32) * 64 + sw] = a1;
    *(bf8_t*)&Bs[srow * 64 + sw] = w0;
    *(bf8_t*)&Bs[(srow + 32) * 64 + sw] = w1;
    __syncthreads();
#pragma unroll
    for (int ks = 0; ks < 2; ++ks) {
      const int arow = w * 16 + lr;
      bf8_t af = *(const bf8_t*)&As[arow * 64 + 8 * ((ks * 4 + lg) ^ (arow & 7))];
#pragma unroll
      for (int nf = 0; nf < 4; ++nf) {
        const int brow = nf * 16 + lr;
        bf8_t bfr = *(const bf8_t*)&Bs[brow * 64 + 8 * ((ks * 4 + lg) ^ (brow & 7))];
        acc[nf] = __builtin_amdgcn_mfma_f32_16x16x32_bf16(af, bfr, acc[nf], 0, 0, 0);
      }
    }
  }
#pragma unroll
  for (int nf = 0; nf < 4; ++nf) {
    const int j = j0 + nf * 16 + lr;
    const float bb = bias[j];
#pragma unroll
    for (int r = 0; r < 4; ++r)
      C[(size_t)(i0 + w * 16 + lg * 4 + r) * D + j] = acc[nf][r] + bb;
  }
}

// ---------------- final expmap0 over full rows (512) -> d_out --------------
__global__ __launch_bounds__(256) void expmap_rows_full(
    const float* __restrict__ in, float* __restrict__ out) {
  const int row = blockIdx.x;
  const float2 xv = *(const float2*)(in + (size_t)row * D + threadIdx.x * 2);
  float s = xv.x * xv.x + xv.y * xv.y;
  __shared__ float sh[4];
  float ws = waveSum(s);
  if ((threadIdx.x & 63) == 0) sh[threadIdx.x >> 6] = ws;
  __syncthreads();
  float tot = sh[0] + sh[1] + sh[2] + sh[3];
  float n = fmaxf(sqrtf(tot), EPSF);
  float fac = fminf(tanh_pos(n), MAXN) / n;
  float2 o = make_float2(xv.x * fac, xv.y * fac);
  *(float2*)(out + (size_t)row * D + threadIdx.x * 2) = o;
}

}  // namespace

extern "C" void kernel_launch(void* const* d_in, const int* in_sizes, int n_in,
                              void* d_out, int out_size, void* d_ws,
                              size_t ws_size, hipStream_t stream) {
  const float* q = (const float*)d_in[0];
  const float* k = (const float*)d_in[1];
  const float* v = (const float*)d_in[2];
  const float* Wq = (const float*)d_in[3];
  const float* bq = (const float*)d_in[4];
  const float* Wk = (const float*)d_in[5];
  const float* bk = (const float*)d_in[6];
  const float* Wv = (const float*)d_in[7];
  const float* bv = (const float*)d_in[8];
  const float* Wo = (const float*)d_in[9];
  const float* bo = (const float*)d_in[10];
  float* out = (float*)d_out;

  char* w8 = (char*)d_ws;
  u16* tanb = (u16*)(w8 + 0);               // 3 MB  q|k|v tangent bf16
  u16* Wbf = (u16*)(w8 + 3145728);          // 2 MB  Wq|Wk|Wv|Wo bf16
  u16* hq = (u16*)(w8 + 5242880);           // 1 MB
  u16* hk = (u16*)(w8 + 6291456);           // 1 MB
  u16* vT = (u16*)(w8 + 7340032);           // 1 MB  [bh*64+d][s] f16
  float* qn2 = (float*)(w8 + 8388608);      // 32 KB
  float* kn2 = (float*)(w8 + 8421376);      // 32 KB
  u16* ctx = (u16*)(w8 + 8454144);          // 1 MB  bf16
  float* olin = (float*)(w8 + 9502720);     // 2 MB  fp32

  prep<<<dim3(BS, 4), 256, 0, stream>>>(q, k, v, Wq, Wk, Wv, Wo, tanb, Wbf);
  gemm_qkv<<<dim3(8, 16, 3), 256, 0, stream>>>(tanb, Wbf, bq, bk, bv, hq, hk,
                                               vT, qn2, kn2);
  fused_attn<<<dim3(8, 16), 256, 0, stream>>>(hq, hk, vT, qn2, kn2, ctx);
  gemm_out<<<dim3(8, 16), 256, 0, stream>>>(ctx, Wbf + 3 * D * D, bo, olin);
  expmap_rows_full<<<dim3(BS), 256, 0, stream>>>(olin, out);
}

// Round 5
// 48.555 us; speedup vs baseline: 2.7225x; 1.1529x over previous
//
#include <hip/hip_runtime.h>
#include <cmath>

#define DEV static __device__ __forceinline__

namespace {

constexpr int B = 2, S = 512, D = 512, H = 8;  // dh = 64
constexpr int BS = B * S;                      // 1024 token rows
constexpr float EPSF = 1e-5f;
constexpr float MAXN = 1.0f - 1e-3f;           // MAX_NORM / sqrt(c)
constexpr int NSPLIT = 4;                      // K-splits in fused attention
constexpr int TPS = 8 / NSPLIT;                // 64-wide K-tiles per split

typedef unsigned short u16;
typedef unsigned int u32;
typedef __attribute__((ext_vector_type(8))) short bf8_t;    // bf16x8 (16B)
typedef __attribute__((ext_vector_type(8))) _Float16 h8_t;  // f16x8
typedef __attribute__((ext_vector_type(4))) float f4_t;

DEV float waveSum(float v) {
#pragma unroll
  for (int o = 32; o > 0; o >>= 1) v += __shfl_xor(v, o, 64);
  return v;
}

DEV u16 f2bf(float f) {  // RNE bf16
  u32 x = __float_as_uint(f);
  u32 r = x + 0x7fffu + ((x >> 16) & 1u);
  return (u16)(r >> 16);
}
DEV float bf2f(u16 u) { return __uint_as_float(((u32)u) << 16); }
DEV u16 f2h(float f) {
  _Float16 h = (_Float16)f;
  u16 u;
  __builtin_memcpy(&u, &h, 2);
  return u;
}
DEV float tanh_pos(float n) {  // tanh for n >= 0
  float e = __builtin_amdgcn_exp2f(2.8853900817779268f * n);  // e^(2n)
  return (e - 1.f) / (e + 1.f);
}

// ---------------- prep: logmap0 rows (y=0..2) + weight bf16 conv (y=3) -----
__global__ __launch_bounds__(256) void prep(
    const float* __restrict__ q, const float* __restrict__ k,
    const float* __restrict__ v, const float* __restrict__ Wq,
    const float* __restrict__ Wk, const float* __restrict__ Wv,
    const float* __restrict__ Wo, u16* __restrict__ tanb,
    u16* __restrict__ Wbf) {
  const int y = blockIdx.y;
  if (y == 3) {
    const int x = blockIdx.x;  // 0..1023 -> 4 matrices x 256 blocks
    const int wi = x >> 8;
    const float* Wsel = wi == 0 ? Wq : (wi == 1 ? Wk : (wi == 2 ? Wv : Wo));
    const int idx = ((x & 255) * 256 + threadIdx.x) * 4;
    float4 val = *(const float4*)(Wsel + idx);
    ushort4 o;
    o.x = f2bf(val.x); o.y = f2bf(val.y); o.z = f2bf(val.z); o.w = f2bf(val.w);
    *(ushort4*)(Wbf + (size_t)wi * D * D + idx) = o;
    return;
  }
  const float* in = y == 0 ? q : (y == 1 ? k : v);
  u16* out = tanb + (size_t)y * BS * D;
  const int row = blockIdx.x;
  const float2 xv = *(const float2*)(in + (size_t)row * D + threadIdx.x * 2);
  float s = xv.x * xv.x + xv.y * xv.y;
  __shared__ float sh[4];
  float ws = waveSum(s);
  if ((threadIdx.x & 63) == 0) sh[threadIdx.x >> 6] = ws;
  __syncthreads();
  float tot = sh[0] + sh[1] + sh[2] + sh[3];
  float n = fmaxf(sqrtf(tot), EPSF);
  float z = fminf(n, 1.0f - EPSF);
  // artanh(z) = 0.5*ln((1+z)/(1-z)) = 0.5*ln2*log2(...)
  float fac = 0.34657359027997264f *
              __builtin_amdgcn_logf((1.0f + z) / (1.0f - z)) / n;
  ushort2 o;
  o.x = f2bf(xv.x * fac);
  o.y = f2bf(xv.y * fac);
  *(ushort2*)(out + (size_t)row * D + threadIdx.x * 2) = o;
}

// ---------------- QKV GEMM + fused expmap / V-transpose epilogues ----------
// z=0: q -> hq bf16 + qn2 ; z=1: k -> hk bf16 + kn2 ; z=2: v -> vT f16.
// qn2/kn2 layout: [H][BS] (contiguous in token for fused_attn reads).
__global__ __launch_bounds__(256) void gemm_qkv(
    const u16* __restrict__ tanb, const u16* __restrict__ Wbf,
    const float* __restrict__ bq, const float* __restrict__ bk,
    const float* __restrict__ bv, u16* __restrict__ hq, u16* __restrict__ hk,
    u16* __restrict__ vT, float* __restrict__ qn2, float* __restrict__ kn2) {
  const int z = blockIdx.z;
  const u16* A = tanb + (size_t)z * BS * D;
  const u16* W = Wbf + (size_t)z * D * D;
  const float* bias = z == 0 ? bq : (z == 1 ? bk : bv);
  const int i0 = blockIdx.y * 64, j0 = blockIdx.x * 64, h = blockIdx.x;
  __shared__ __align__(16) u16 As[4096], Bs[4096];
  const int tid = threadIdx.x;
  const int w = tid >> 6, l = tid & 63, lg = l >> 4, lr = l & 15;
  const int srow = tid >> 3, scb = tid & 7;
  f4_t acc[4] = {{0, 0, 0, 0}, {0, 0, 0, 0}, {0, 0, 0, 0}, {0, 0, 0, 0}};
  for (int kt = 0; kt < D; kt += 64) {
    bf8_t a0 = *(const bf8_t*)(A + (size_t)(i0 + srow) * D + kt + scb * 8);
    bf8_t a1 = *(const bf8_t*)(A + (size_t)(i0 + srow + 32) * D + kt + scb * 8);
    bf8_t w0 = *(const bf8_t*)(W + (size_t)(j0 + srow) * D + kt + scb * 8);
    bf8_t w1 = *(const bf8_t*)(W + (size_t)(j0 + srow + 32) * D + kt + scb * 8);
    __syncthreads();
    const int sw = 8 * (scb ^ (srow & 7));
    *(bf8_t*)&As[srow * 64 + sw] = a0;
    *(bf8_t*)&As[(srow + 32) * 64 + sw] = a1;
    *(bf8_t*)&Bs[srow * 64 + sw] = w0;
    *(bf8_t*)&Bs[(srow + 32) * 64 + sw] = w1;
    __syncthreads();
#pragma unroll
    for (int ks = 0; ks < 2; ++ks) {
      const int arow = w * 16 + lr;
      bf8_t af = *(const bf8_t*)&As[arow * 64 + 8 * ((ks * 4 + lg) ^ (arow & 7))];
#pragma unroll
      for (int nf = 0; nf < 4; ++nf) {
        const int brow = nf * 16 + lr;
        bf8_t bfr = *(const bf8_t*)&Bs[brow * 64 + 8 * ((ks * 4 + lg) ^ (brow & 7))];
        acc[nf] = __builtin_amdgcn_mfma_f32_16x16x32_bf16(af, bfr, acc[nf], 0, 0, 0);
      }
    }
  }
  float c[4][4];
#pragma unroll
  for (int nf = 0; nf < 4; ++nf) {
    const float bb = bias[j0 + nf * 16 + lr];
#pragma unroll
    for (int r = 0; r < 4; ++r) c[nf][r] = acc[nf][r] + bb;
  }
  if (z < 2) {
    float part[4] = {0, 0, 0, 0};
#pragma unroll
    for (int nf = 0; nf < 4; ++nf)
#pragma unroll
      for (int r = 0; r < 4; ++r) part[r] += c[nf][r] * c[nf][r];
#pragma unroll
    for (int off = 1; off < 16; off <<= 1)
#pragma unroll
      for (int r = 0; r < 4; ++r) part[r] += __shfl_xor(part[r], off, 64);
    float fac[4];
#pragma unroll
    for (int r = 0; r < 4; ++r) {
      float n = fmaxf(sqrtf(part[r]), EPSF);
      fac[r] = fminf(tanh_pos(n), MAXN) / n;
    }
    u16 yb[4][4];
    float p2[4] = {0, 0, 0, 0};
#pragma unroll
    for (int nf = 0; nf < 4; ++nf)
#pragma unroll
      for (int r = 0; r < 4; ++r) {
        u16 t = f2bf(c[nf][r] * fac[r]);
        yb[nf][r] = t;
        float yf = bf2f(t);
        p2[r] += yf * yf;  // norm^2 of the rounded point
      }
#pragma unroll
    for (int off = 1; off < 16; off <<= 1)
#pragma unroll
      for (int r = 0; r < 4; ++r) p2[r] += __shfl_xor(p2[r], off, 64);
    u16* dst = z == 0 ? hq : hk;
    float* n2o = z == 0 ? qn2 : kn2;
#pragma unroll
    for (int nf = 0; nf < 4; ++nf)
#pragma unroll
      for (int r = 0; r < 4; ++r)
        dst[(size_t)(i0 + w * 16 + lg * 4 + r) * D + j0 + nf * 16 + lr] = yb[nf][r];
    if (lr == 0)
#pragma unroll
      for (int r = 0; r < 4; ++r)
        n2o[h * BS + i0 + w * 16 + lg * 4 + r] = p2[r];
  } else {
    // V: f16, transpose via LDS -> vT[(b*8+h)*64 + d][s]
    __syncthreads();
#pragma unroll
    for (int nf = 0; nf < 4; ++nf)
#pragma unroll
      for (int r = 0; r < 4; ++r) {
        const int prow = w * 16 + lg * 4 + r;   // local token s
        const int pcol = nf * 16 + lr;          // local d
        As[prow * 64 + 8 * ((pcol >> 3) ^ (prow & 7)) + (pcol & 7)] = f2h(c[nf][r]);
      }
    __syncthreads();
    const int d = tid >> 2, s0 = (tid & 3) * 16;
    const int b = i0 >> 9, sb = (i0 & 511) + s0;
    bf8_t o0, o1;
#pragma unroll
    for (int j = 0; j < 8; ++j) {
      const int s = s0 + j;
      o0[j] = (short)As[s * 64 + 8 * ((d >> 3) ^ (s & 7)) + (d & 7)];
    }
#pragma unroll
    for (int j = 0; j < 8; ++j) {
      const int s = s0 + 8 + j;
      o1[j] = (short)As[s * 64 + 8 * ((d >> 3) ^ (s & 7)) + (d & 7)];
    }
    u16* dst = vT + ((size_t)((b * 8 + h) * 64 + d)) * S + sb;
    *(bf8_t*)dst = o0;
    *(bf8_t*)(dst + 8) = o1;
  }
}

// ---------------- fused attention, split-K, 1 wave / 16 Q-rows -------------
// No barriers: K/V fragments load global->VGPR directly (L2-resident),
// LDS only for the same-wave P bounce (double-buffered).
// Partial outputs per split: Opart[sp][bh][q][d] fp32, rpart[sp][bh][q].
__global__ __launch_bounds__(64) void fused_attn_sk(
    const u16* __restrict__ hq, const u16* __restrict__ hk,
    const u16* __restrict__ vT, const float* __restrict__ qn2,
    const float* __restrict__ kn2, float* __restrict__ Opart,
    float* __restrict__ rpart) {
  const int bh = blockIdx.z, b = bh >> 3, h = bh & 7;
  const int i0 = blockIdx.x * 16;
  const int sp = blockIdx.y;
  __shared__ __align__(16) u16 Ps[2][16 * 64];
  const int l = threadIdx.x, lg = l >> 4, lr = l & 15;
  bf8_t qf[2];
#pragma unroll
  for (int ks = 0; ks < 2; ++ks)
    qf[ks] = *(const bf8_t*)(hq + (size_t)(b * S + i0 + lr) * D + h * 64 +
                             ks * 32 + lg * 8);
  float qq[4];
#pragma unroll
  for (int r = 0; r < 4; ++r) qq[r] = qn2[h * BS + b * S + i0 + lg * 4 + r];
  f4_t acc_o[4] = {{0, 0, 0, 0}, {0, 0, 0, 0}, {0, 0, 0, 0}, {0, 0, 0, 0}};
  float rsum[4] = {0, 0, 0, 0};
#pragma unroll
  for (int t = 0; t < TPS; ++t) {
    const int kt = sp * TPS + t;
    const int kb = b * S + kt * 64;
    bf8_t kf[2][4], vf[2][4];
#pragma unroll
    for (int ks = 0; ks < 2; ++ks)
#pragma unroll
      for (int nf = 0; nf < 4; ++nf) {
        kf[ks][nf] = *(const bf8_t*)(hk + (size_t)(kb + nf * 16 + lr) * D +
                                     h * 64 + ks * 32 + lg * 8);
        vf[ks][nf] = *(const bf8_t*)(vT + (size_t)(bh * 64 + nf * 16 + lr) * S +
                                     kt * 64 + ks * 32 + lg * 8);
      }
    float kn[4];
#pragma unroll
    for (int nf = 0; nf < 4; ++nf) kn[nf] = kn2[h * BS + kb + nf * 16 + lr];
    f4_t sa[4] = {{0, 0, 0, 0}, {0, 0, 0, 0}, {0, 0, 0, 0}, {0, 0, 0, 0}};
#pragma unroll
    for (int ks = 0; ks < 2; ++ks)
#pragma unroll
      for (int nf = 0; nf < 4; ++nf)
        sa[nf] = __builtin_amdgcn_mfma_f32_16x16x32_bf16(qf[ks], kf[ks][nf],
                                                         sa[nf], 0, 0, 0);
    u16* Pb = Ps[t & 1];
    float ps[4] = {0, 0, 0, 0};
#pragma unroll
    for (int nf = 0; nf < 4; ++nf) {
      const float kk = kn[nf];
#pragma unroll
      for (int r = 0; r < 4; ++r) {
        const float tt = sa[nf][r];
        float num = fmaxf(qq[r] - 2.f * tt + kk, 0.f);
        float den = fmaxf(1.f - 2.f * tt + qq[r] * kk, EPSF);
        float rr = fminf(fmaxf(sqrtf(num / den), EPSF), MAXN);
        // p = ((1-r)/(1+r))^(1/8)
        float p = __builtin_amdgcn_exp2f(
            0.125f * __builtin_amdgcn_logf((1.f - rr) / (1.f + rr)));
        ps[r] += p;
        const int prow = lg * 4 + r, pcol = nf * 16 + lr;
        Pb[prow * 64 + 8 * ((pcol >> 3) ^ (prow & 7)) + (pcol & 7)] = f2h(p);
      }
    }
#pragma unroll
    for (int off = 1; off < 16; off <<= 1)
#pragma unroll
      for (int r = 0; r < 4; ++r) ps[r] += __shfl_xor(ps[r], off, 64);
#pragma unroll
    for (int r = 0; r < 4; ++r) rsum[r] += ps[r];
#pragma unroll
    for (int ks = 0; ks < 2; ++ks) {
      h8_t pa = *(const h8_t*)&Pb[lr * 64 + 8 * ((ks * 4 + lg) ^ (lr & 7))];
#pragma unroll
      for (int nf = 0; nf < 4; ++nf)
        acc_o[nf] = __builtin_amdgcn_mfma_f32_16x16x32_f16(pa, vf[ks][nf],
                                                           acc_o[nf], 0, 0, 0);
    }
  }
  float* Ob = Opart + ((size_t)(sp * 16 + bh) * S + i0) * 64;
#pragma unroll
  for (int nf = 0; nf < 4; ++nf)
#pragma unroll
    for (int r = 0; r < 4; ++r)
      Ob[(lg * 4 + r) * 64 + nf * 16 + lr] = acc_o[nf][r];
  if (lr == 0)
#pragma unroll
    for (int r = 0; r < 4; ++r)
      rpart[(size_t)(sp * 16 + bh) * S + i0 + lg * 4 + r] = rsum[r];
}

// ---------------- combine split-K partials -> ctx bf16 ---------------------
__global__ __launch_bounds__(256) void combine_sk(
    const float* __restrict__ Opart, const float* __restrict__ rpart,
    u16* __restrict__ ctx) {
  const int e2 = blockIdx.x * 256 + threadIdx.x;  // 0..262143
  const int idx = e2 * 2;                         // into [16][512][64]
  const int bh = idx >> 15;
  const int rem = idx & 32767;
  const int qrow = rem >> 6, d = rem & 63;
  float rt = 0.f;
#pragma unroll
  for (int sp = 0; sp < NSPLIT; ++sp)
    rt += rpart[(size_t)(sp * 16 + bh) * S + qrow];
  float ox = 0.f, oy = 0.f;
#pragma unroll
  for (int sp = 0; sp < NSPLIT; ++sp) {
    float2 t = *(const float2*)&Opart[((size_t)(sp * 16 + bh) * S + qrow) * 64 + d];
    ox += t.x; oy += t.y;
  }
  float inv = 1.f / rt;
  ushort2 ov;
  ov.x = f2bf(ox * inv);
  ov.y = f2bf(oy * inv);
  const int token = (bh >> 3) * S + qrow, col = (bh & 7) * 64 + d;
  *(ushort2*)&ctx[(size_t)token * D + col] = ov;
}

// ---------------- out projection: ctx @ Wo^T + bo -> fp32 ------------------
__global__ __launch_bounds__(256) void gemm_out(
    const u16* __restrict__ A, const u16* __restrict__ W,
    const float* __restrict__ bias, float* __restrict__ C) {
  const int i0 = blockIdx.y * 64, j0 = blockIdx.x * 64;
  __shared__ __align__(16) u16 As[4096], Bs[4096];
  const int tid = threadIdx.x;
  const int w = tid >> 6, l = tid & 63, lg = l >> 4, lr = l & 15;
  const int srow = tid >> 3, scb = tid & 7;
  f4_t acc[4] = {{0, 0, 0, 0}, {0, 0, 0, 0}, {0, 0, 0, 0}, {0, 0, 0, 0}};
  for (int kt = 0; kt < D; kt += 64) {
    bf8_t a0 = *(const bf8_t*)(A + (size_t)(i0 + srow) * D + kt + scb * 8);
    bf8_t a1 = *(const bf8_t*)(A + (size_t)(i0 + srow + 32) * D + kt + scb * 8);
    bf8_t w0 = *(const bf8_t*)(W + (size_t)(j0 + srow) * D + kt + scb * 8);
    bf8_t w1 = *(const bf8_t*)(W + (size_t)(j0 + srow + 32) * D + kt + scb * 8);
    __syncthreads();
    const int sw = 8 * (scb ^ (srow & 7));
    *(bf8_t*)&As[srow * 64 + sw] = a0;
    *(bf8_t*)&As[(srow + 32) * 64 + sw] = a1;
    *(bf8_t*)&Bs[srow * 64 + sw] = w0;
    *(bf8_t*)&Bs[(srow + 32) * 64 + sw] = w1;
    __syncthreads();
#pragma unroll
    for (int ks = 0; ks < 2; ++ks) {
      const int arow = w * 16 + lr;
      bf8_t af = *(const bf8_t*)&As[arow * 64 + 8 * ((ks * 4 + lg) ^ (arow & 7))];
#pragma unroll
      for (int nf = 0; nf < 4; ++nf) {
        const int brow = nf * 16 + lr;
        bf8_t bfr = *(const bf8_t*)&Bs[brow * 64 + 8 * ((ks * 4 + lg) ^ (brow & 7))];
        acc[nf] = __builtin_amdgcn_mfma_f32_16x16x32_bf16(af, bfr, acc[nf], 0, 0, 0);
      }
    }
  }
#pragma unroll
  for (int nf = 0; nf < 4; ++nf) {
    const int j = j0 + nf * 16 + lr;
    const float bb = bias[j];
#pragma unroll
    for (int r = 0; r < 4; ++r)
      C[(size_t)(i0 + w * 16 + lg * 4 + r) * D + j] = acc[nf][r] + bb;
  }
}

// ---------------- final expmap0 over full rows (512) -> d_out --------------
__global__ __launch_bounds__(256) void expmap_rows_full(
    const float* __restrict__ in, float* __restrict__ out) {
  const int row = blockIdx.x;
  const float2 xv = *(const float2*)(in + (size_t)row * D + threadIdx.x * 2);
  float s = xv.x * xv.x + xv.y * xv.y;
  __shared__ float sh[4];
  float ws = waveSum(s);
  if ((threadIdx.x & 63) == 0) sh[threadIdx.x >> 6] = ws;
  __syncthreads();
  float tot = sh[0] + sh[1] + sh[2] + sh[3];
  float n = fmaxf(sqrtf(tot), EPSF);
  float fac = fminf(tanh_pos(n), MAXN) / n;
  float2 o = make_float2(xv.x * fac, xv.y * fac);
  *(float2*)(out + (size_t)row * D + threadIdx.x * 2) = o;
}

}  // namespace

extern "C" void kernel_launch(void* const* d_in, const int* in_sizes, int n_in,
                              void* d_out, int out_size, void* d_ws,
                              size_t ws_size, hipStream_t stream) {
  const float* q = (const float*)d_in[0];
  const float* k = (const float*)d_in[1];
  const float* v = (const float*)d_in[2];
  const float* Wq = (const float*)d_in[3];
  const float* bq = (const float*)d_in[4];
  const float* Wk = (const float*)d_in[5];
  const float* bk = (const float*)d_in[6];
  const float* Wv = (const float*)d_in[7];
  const float* bv = (const float*)d_in[8];
  const float* Wo = (const float*)d_in[9];
  const float* bo = (const float*)d_in[10];
  float* out = (float*)d_out;

  char* w8 = (char*)d_ws;
  u16* tanb = (u16*)(w8 + 0);               // 3 MB  q|k|v tangent bf16
  u16* Wbf = (u16*)(w8 + 3145728);          // 2 MB  Wq|Wk|Wv|Wo bf16
  u16* hq = (u16*)(w8 + 5242880);           // 1 MB
  u16* hk = (u16*)(w8 + 6291456);           // 1 MB
  u16* vT = (u16*)(w8 + 7340032);           // 1 MB  [bh*64+d][s] f16
  float* qn2 = (float*)(w8 + 8388608);      // 32 KB [H][BS]
  float* kn2 = (float*)(w8 + 8421376);      // 32 KB [H][BS]
  u16* ctx = (u16*)(w8 + 8454144);          // 1 MB  bf16
  float* olin = (float*)(w8 + 9502720);     // 2 MB  fp32
  float* Opart = (float*)(w8 + 11534336);   // 8 MB  [NSPLIT][16][512][64]
  float* rpart = (float*)(w8 + 19922944);   // 128 KB [NSPLIT][16][512]

  prep<<<dim3(BS, 4), 256, 0, stream>>>(q, k, v, Wq, Wk, Wv, Wo, tanb, Wbf);
  gemm_qkv<<<dim3(8, 16, 3), 256, 0, stream>>>(tanb, Wbf, bq, bk, bv, hq, hk,
                                               vT, qn2, kn2);
  fused_attn_sk<<<dim3(32, NSPLIT, 16), 64, 0, stream>>>(hq, hk, vT, qn2, kn2,
                                                         Opart, rpart);
  combine_sk<<<dim3(1024), 256, 0, stream>>>(Opart, rpart, ctx);
  gemm_out<<<dim3(8, 16), 256, 0, stream>>>(ctx, Wbf + 3 * D * D, bo, olin);
  expmap_rows_full<<<dim3(BS), 256, 0, stream>>>(olin, out);
}